// Round 1
// baseline (208.453 us; speedup 1.0000x reference)
//
#include <hip/hip_runtime.h>
#include <hip/hip_bf16.h>
#include <cstdint>
#include <cstddef>

typedef unsigned short u16;
typedef __attribute__((ext_vector_type(8))) short bf16x8;
typedef __attribute__((ext_vector_type(4))) float f32x4;

#define MFMA16(a, b, c) __builtin_amdgcn_mfma_f32_16x16x32_bf16((a), (b), (c), 0, 0, 0)

// ---------- helpers ----------
__device__ __forceinline__ u16 bf16u(float f) {
  union { float f; unsigned u; } x; x.f = f;
  unsigned lsb = (x.u >> 16) & 1u;
  return (u16)((x.u + 0x7fffu + lsb) >> 16);   // RNE
}

__device__ __forceinline__ void gload16(const void* g, void* l) {
  __builtin_amdgcn_global_load_lds(
      (const __attribute__((address_space(1))) unsigned int*)g,
      (__attribute__((address_space(3))) unsigned int*)l, 16, 0, 0);
}

// XOR-swizzled element offset for [rows][64] bf16 LDS tiles (128B rows, 8x16B units).
// unit u in [0,8): returns element index of the 16B-aligned fragment start.
__device__ __forceinline__ int swz128(int row, int u) {
  return row * 64 + ((u ^ (row & 7)) << 3);
}

// ---------- fp32 -> bf16 converts ----------
__global__ __launch_bounds__(256) void cvt_qkv(const float* __restrict__ a,
                                               const float* __restrict__ b,
                                               const float* __restrict__ c,
                                               u16* __restrict__ oa,
                                               u16* __restrict__ ob,
                                               u16* __restrict__ oc) {
  const int z = blockIdx.y;
  const float* s = (z == 0) ? a : (z == 1 ? b : c);
  u16* d = (z == 0) ? oa : (z == 1 ? ob : oc);
  const int i = (blockIdx.x * 256 + threadIdx.x) * 4;
  float4 f = *(const float4*)(s + i);
  ushort4 o = make_ushort4(bf16u(f.x), bf16u(f.y), bf16u(f.z), bf16u(f.w));
  *(ushort4*)(d + i) = o;
}

__global__ __launch_bounds__(256) void cvt_w(const float* __restrict__ a,
                                             const float* __restrict__ b,
                                             const float* __restrict__ c,
                                             const float* __restrict__ d,
                                             u16* __restrict__ oa,
                                             u16* __restrict__ ob,
                                             u16* __restrict__ oc,
                                             u16* __restrict__ od) {
  const int z = blockIdx.y;
  const float* s = (z == 0) ? a : (z == 1 ? b : (z == 2 ? c : d));
  u16* o = (z == 0) ? oa : (z == 1 ? ob : (z == 2 ? oc : od));
  const int i = (blockIdx.x * 256 + threadIdx.x) * 4;
  float4 f = *(const float4*)(s + i);
  ushort4 v = make_ushort4(bf16u(f.x), bf16u(f.y), bf16u(f.z), bf16u(f.w));
  *(ushort4*)(o + i) = v;
}

// ---------- GEMM: C = A(bf16,[4096x1024]) * W^T(bf16,[1024x1024] row-major [N,K]) + bias ----------
// MODE 0: QKV fused via blockIdx.z. z==0: Q, scaled 0.125, out [B,NH,S,64] bf16
//                                   z==1: K, out [B,NH,S,64] bf16
//                                   z==2: V, out [B,NH,64,S] bf16 (transposed)
// MODE 1: out-projection, fp32 out [4096,1024] (natural), uses slot-0 pointers.
template <int MODE>
__global__ __launch_bounds__(256) void mha_gemm(
    const u16* __restrict__ A0, const u16* __restrict__ A1, const u16* __restrict__ A2,
    const u16* __restrict__ W0, const u16* __restrict__ W1, const u16* __restrict__ W2,
    const float* __restrict__ b0, const float* __restrict__ b1, const float* __restrict__ b2,
    u16* __restrict__ o0, u16* __restrict__ o1, u16* __restrict__ o2,
    float* __restrict__ of) {
  const int tid = threadIdx.x;
  const int lane = tid & 63;
  const int wid = tid >> 6;
  const int wr = wid >> 1, wc = wid & 1;
  const int bm = blockIdx.x, bn = blockIdx.y;
  const int z = (MODE == 0) ? blockIdx.z : 0;

  const u16* Ap = (z == 0) ? A0 : (z == 1 ? A1 : A2);
  const u16* Wp = (z == 0) ? W0 : (z == 1 ? W1 : W2);
  const float* bias = (z == 0) ? b0 : (z == 1 ? b1 : b2);
  u16* ob = (z == 0) ? o0 : (z == 1 ? o1 : o2);

  __shared__ __align__(16) u16 Als[128 * 64];
  __shared__ __align__(16) u16 Bls[128 * 64];

  const u16* Abase = Ap + (size_t)bm * 128 * 1024;
  const u16* Wbase = Wp + (size_t)bn * 128 * 1024;

  f32x4 acc[4][4] = {};

  for (int kt = 0; kt < 16; ++kt) {
    const int k0 = kt * 64;
    __syncthreads();
#pragma unroll
    for (int i = 0; i < 4; ++i) {
      int L = i * 256 + tid;          // 16B unit index within tile
      int r = L >> 3;                 // row (0..127)
      int c8 = (L & 7) ^ (r & 7);     // inverse-swizzled source column unit
      gload16(Abase + (size_t)r * 1024 + k0 + c8 * 8, &Als[L * 8]);
      gload16(Wbase + (size_t)r * 1024 + k0 + c8 * 8, &Bls[L * 8]);
    }
    __syncthreads();
#pragma unroll
    for (int ks = 0; ks < 2; ++ks) {
      bf16x8 af[4], bw[4];
#pragma unroll
      for (int m = 0; m < 4; ++m)
        af[m] = *(const bf16x8*)&Als[swz128(wr * 64 + m * 16 + (lane & 15), ks * 4 + (lane >> 4))];
#pragma unroll
      for (int n = 0; n < 4; ++n)
        bw[n] = *(const bf16x8*)&Bls[swz128(wc * 64 + n * 16 + (lane & 15), ks * 4 + (lane >> 4))];
#pragma unroll
      for (int m = 0; m < 4; ++m)
#pragma unroll
        for (int n = 0; n < 4; ++n)
          acc[m][n] = MFMA16(af[m], bw[n], acc[m][n]);
    }
  }

  const float scl = (MODE == 0 && z == 0) ? 0.125f : 1.0f;
#pragma unroll
  for (int n = 0; n < 4; ++n) {
    const int col = bn * 128 + wc * 64 + n * 16 + (lane & 15);
    const float bb = bias[col];
#pragma unroll
    for (int m = 0; m < 4; ++m) {
#pragma unroll
      for (int r = 0; r < 4; ++r) {
        const int row = bm * 128 + wr * 64 + m * 16 + ((lane >> 4) << 2) + r;
        float val = acc[m][n][r] + bb;
        if (MODE == 0) {
          val *= scl;
          const int bi = row >> 11, ss = row & 2047;
          const int hh = col >> 6, dd = col & 63;
          size_t off;
          if (z == 2) off = (((size_t)(bi * 16 + hh)) * 64 + dd) * 2048 + ss;   // V^T
          else        off = (((size_t)(bi * 16 + hh)) * 2048 + ss) * 64 + dd;   // Q,K
          ob[off] = bf16u(val);
        } else {
          of[(size_t)row * 1024 + col] = val;
        }
      }
    }
  }
}

// ---------- flash attention ----------
// Q,K: [B,NH,S,64] bf16 (Q pre-scaled by 0.125). V: [B,NH,64,S] bf16 (transposed).
// Out: [B,S,H] bf16. Block: 4 waves x 16 q-rows = 64 q-rows; KV tile 64.
__global__ __launch_bounds__(256) void attn_kernel(const u16* __restrict__ Qp,
                                                   const u16* __restrict__ Kp,
                                                   const u16* __restrict__ Vp,
                                                   u16* __restrict__ Op) {
  const int tid = threadIdx.x;
  const int lane = tid & 63;
  const int wid = tid >> 6;
  const int qt = blockIdx.x;   // 0..31
  const int h = blockIdx.y;    // 0..15
  const int b = blockIdx.z;    // 0..1

  const u16* Qh = Qp + (size_t)(b * 16 + h) * (2048 * 64);
  const u16* Kh = Kp + (size_t)(b * 16 + h) * (2048 * 64);
  const u16* Vh = Vp + (size_t)(b * 16 + h) * (64 * 2048);

  __shared__ __align__(16) u16 Kls[64 * 64];
  __shared__ __align__(16) u16 Vls[64 * 64];   // holds V^T tile: [d (64)][kk (64)]
  __shared__ __align__(16) u16 Pls[4][16 * 64];

  const int qrow0 = qt * 64 + wid * 16;

  bf16x8 aq[2];
#pragma unroll
  for (int ks = 0; ks < 2; ++ks)
    aq[ks] = *(const bf16x8*)(Qh + (size_t)(qrow0 + (lane & 15)) * 64 + ks * 32 + ((lane >> 4) << 3));

  float mrun[4], lrun[4];
  f32x4 oacc[4] = {};
#pragma unroll
  for (int r = 0; r < 4; ++r) { mrun[r] = -__builtin_inff(); lrun[r] = 0.f; }

  for (int kt = 0; kt < 32; ++kt) {
    __syncthreads();
#pragma unroll
    for (int i = 0; i < 2; ++i) {
      int L = i * 256 + tid;
      int r = L >> 3;
      int c8 = (L & 7) ^ (r & 7);
      gload16(Kh + (size_t)kt * 4096 + r * 64 + c8 * 8, &Kls[L * 8]);          // K rows
      gload16(Vh + (size_t)r * 2048 + kt * 64 + c8 * 8, &Vls[L * 8]);          // V^T rows (d)
    }
    __syncthreads();

    // S = Q K^T  (16 q-rows x 64 keys per wave)
    f32x4 s[4];
#pragma unroll
    for (int n = 0; n < 4; ++n) {
      const int krow = n * 16 + (lane & 15);
      f32x4 sa = {0.f, 0.f, 0.f, 0.f};
#pragma unroll
      for (int ks = 0; ks < 2; ++ks) {
        bf16x8 kb = *(const bf16x8*)&Kls[swz128(krow, ks * 4 + (lane >> 4))];
        sa = MFMA16(aq[ks], kb, sa);
      }
      s[n] = sa;
    }

    // online softmax (rows live in 16-lane groups; reg r -> row (lane>>4)*4+r)
    float fac[4];
#pragma unroll
    for (int r = 0; r < 4; ++r) {
      float t = fmaxf(fmaxf(s[0][r], s[1][r]), fmaxf(s[2][r], s[3][r]));
      t = fmaxf(t, __shfl_xor(t, 1));
      t = fmaxf(t, __shfl_xor(t, 2));
      t = fmaxf(t, __shfl_xor(t, 4));
      t = fmaxf(t, __shfl_xor(t, 8));
      const float mnew = fmaxf(mrun[r], t);
      fac[r] = __expf(mrun[r] - mnew);
      float ps = 0.f;
#pragma unroll
      for (int n = 0; n < 4; ++n) {
        float e = __expf(s[n][r] - mnew);
        s[n][r] = e;
        ps += e;
      }
      ps += __shfl_xor(ps, 1);
      ps += __shfl_xor(ps, 2);
      ps += __shfl_xor(ps, 4);
      ps += __shfl_xor(ps, 8);
      lrun[r] = lrun[r] * fac[r] + ps;
      mrun[r] = mnew;
    }
#pragma unroll
    for (int n = 0; n < 4; ++n)
#pragma unroll
      for (int r = 0; r < 4; ++r)
        oacc[n][r] *= fac[r];

    // P -> bf16 -> per-wave swizzled LDS (for PV A-fragment)
#pragma unroll
    for (int n = 0; n < 4; ++n)
#pragma unroll
      for (int r = 0; r < 4; ++r) {
        const int prow = ((lane >> 4) << 2) + r;
        const int pcol = n * 16 + (lane & 15);
        Pls[wid][prow * 64 + (((pcol >> 3) ^ (prow & 7)) << 3) + (pcol & 7)] = bf16u(s[n][r]);
      }
    __asm__ volatile("s_waitcnt lgkmcnt(0)" ::: "memory");

    // O += P V
    bf16x8 pa[2];
#pragma unroll
    for (int ks = 0; ks < 2; ++ks)
      pa[ks] = *(const bf16x8*)&Pls[wid][swz128(lane & 15, ks * 4 + (lane >> 4))];
#pragma unroll
    for (int n = 0; n < 4; ++n) {
      const int drow = n * 16 + (lane & 15);
#pragma unroll
      for (int ks = 0; ks < 2; ++ks) {
        bf16x8 vb = *(const bf16x8*)&Vls[swz128(drow, ks * 4 + (lane >> 4))];
        oacc[n] = MFMA16(pa[ks], vb, oacc[n]);
      }
    }
  }

  // epilogue: normalize and store [B,S,H] bf16
#pragma unroll
  for (int n = 0; n < 4; ++n) {
    const int d = n * 16 + (lane & 15);
#pragma unroll
    for (int r = 0; r < 4; ++r) {
      const int row = qrow0 + ((lane >> 4) << 2) + r;
      const float val = oacc[n][r] / lrun[r];
      Op[((size_t)b * 2048 + row) * 1024 + h * 64 + d] = bf16u(val);
    }
  }
}

// ---------- launch ----------
extern "C" void kernel_launch(void* const* d_in, const int* in_sizes, int n_in,
                              void* d_out, int out_size, void* d_ws, size_t ws_size,
                              hipStream_t stream) {
  const float* q  = (const float*)d_in[0];
  const float* k  = (const float*)d_in[1];
  const float* v  = (const float*)d_in[2];
  const float* Wq = (const float*)d_in[3];
  const float* bq = (const float*)d_in[4];
  const float* Wk = (const float*)d_in[5];
  const float* bk = (const float*)d_in[6];
  const float* Wv = (const float*)d_in[7];
  const float* bv = (const float*)d_in[8];
  const float* Wo = (const float*)d_in[9];
  const float* bo = (const float*)d_in[10];

  u16* ws = (u16*)d_ws;
  const size_t NX = 4194304;  // B*S*H
  const size_t NW = 1048576;  // H*H
  u16* xq  = ws;
  u16* xk  = xq + NX;
  u16* xv  = xk + NX;
  u16* wqb = xv + NX;
  u16* wkb = wqb + NW;
  u16* wvb = wkb + NW;
  u16* wob = wvb + NW;
  u16* Qp  = wob + NW;
  u16* Kp  = Qp + NX;
  u16* Vp  = Kp + NX;
  u16* Ao  = Vp + NX;          // total 32M u16 = 64 MB

  cvt_qkv<<<dim3(4096, 3), 256, 0, stream>>>(q, k, v, xq, xk, xv);
  cvt_w<<<dim3(1024, 4), 256, 0, stream>>>(Wq, Wk, Wv, Wo, wqb, wkb, wvb, wob);

  mha_gemm<0><<<dim3(32, 8, 3), 256, 0, stream>>>(xq, xk, xv, wqb, wkb, wvb,
                                                  bq, bk, bv, Qp, Kp, Vp, nullptr);

  attn_kernel<<<dim3(32, 16, 2), 256, 0, stream>>>(Qp, Kp, Vp, Ao);

  mha_gemm<1><<<dim3(32, 8, 1), 256, 0, stream>>>(Ao, nullptr, nullptr, wob, nullptr, nullptr,
                                                  bo, nullptr, nullptr, nullptr, nullptr, nullptr,
                                                  (float*)d_out);
}